// Round 1
// baseline (356.595 us; speedup 1.0000x reference)
//
#include <hip/hip_runtime.h>

#define B_ 64
#define LC 2048
#define LQ 256
#define DD 128

typedef __bf16 bf16;
typedef __bf16 bf16x8 __attribute__((ext_vector_type(8)));
typedef __bf16 bf16x4 __attribute__((ext_vector_type(4)));
typedef float f32x4 __attribute__((ext_vector_type(4)));

#define MFMA16(a, b, c) __builtin_amdgcn_mfma_f32_16x16x32_bf16((a), (b), (c), 0, 0, 0)

// ---------------------------------------------------------------------------
// K1: prep C: Cw = bf16(C * w4mlu), CbT = bf16(C)^T per batch, sub0 = C @ w4C
// grid: (B*32) blocks, 256 threads; tile = 64 c-rows x 128 d
// ---------------------------------------------------------------------------
__global__ __launch_bounds__(256) void k_prep_c(const float* __restrict__ C,
    const float* __restrict__ w4C, const float* __restrict__ w4mlu,
    bf16* __restrict__ Cw, bf16* __restrict__ CbT, float* __restrict__ sub0)
{
    __shared__ bf16 lds[64][DD + 2];
    int b = blockIdx.x >> 5, ct = blockIdx.x & 31;
    int c0 = ct * 64;
    int t = threadIdx.x;
    int r = t >> 2, cb = (t & 3) * 32;
    size_t rowoff = ((size_t)(b * LC + c0 + r)) * DD + cb;
    const float4* src = (const float4*)(C + rowoff);
    float s0 = 0.f;
#pragma unroll
    for (int i = 0; i < 8; ++i) {
        float4 v = src[i];
        int d = cb + i * 4;
        bf16x4 cw = { (bf16)(v.x * w4mlu[d]), (bf16)(v.y * w4mlu[d + 1]),
                      (bf16)(v.z * w4mlu[d + 2]), (bf16)(v.w * w4mlu[d + 3]) };
        *(bf16x4*)(Cw + rowoff + i * 4) = cw;
        lds[r][d]     = (bf16)v.x;
        lds[r][d + 1] = (bf16)v.y;
        lds[r][d + 2] = (bf16)v.z;
        lds[r][d + 3] = (bf16)v.w;
        s0 += v.x * w4C[d] + v.y * w4C[d + 1] + v.z * w4C[d + 2] + v.w * w4C[d + 3];
    }
    s0 += __shfl_xor(s0, 1);
    s0 += __shfl_xor(s0, 2);
    if ((t & 3) == 0) sub0[b * LC + c0 + r] = s0;
    __syncthreads();
    int d = t >> 1, cb2 = (t & 1) * 32;
    bf16* dst = CbT + ((size_t)(b * DD + d)) * LC + c0 + cb2;
#pragma unroll
    for (int m = 0; m < 4; ++m) {
        bf16x8 pk;
#pragma unroll
        for (int j = 0; j < 8; ++j) pk[j] = lds[cb2 + m * 8 + j][d];
        *(bf16x8*)(dst + m * 8) = pk;
    }
}

// ---------------------------------------------------------------------------
// K2: prep Q: Qb = bf16(Q), QbT = bf16(Q)^T, sub1 = Q @ w4Q
// grid: (B*4) blocks, 256 threads; tile = 64 q-rows x 128 d
// ---------------------------------------------------------------------------
__global__ __launch_bounds__(256) void k_prep_q(const float* __restrict__ Q,
    const float* __restrict__ w4Q, bf16* __restrict__ Qb, bf16* __restrict__ QbT,
    float* __restrict__ sub1)
{
    __shared__ bf16 lds[64][DD + 2];
    int b = blockIdx.x >> 2, qt = blockIdx.x & 3;
    int q0 = qt * 64;
    int t = threadIdx.x;
    int r = t >> 2, cb = (t & 3) * 32;
    size_t rowoff = ((size_t)(b * LQ + q0 + r)) * DD + cb;
    const float4* src = (const float4*)(Q + rowoff);
    float s1 = 0.f;
#pragma unroll
    for (int i = 0; i < 8; ++i) {
        float4 v = src[i];
        int d = cb + i * 4;
        bf16x4 qv = { (bf16)v.x, (bf16)v.y, (bf16)v.z, (bf16)v.w };
        *(bf16x4*)(Qb + rowoff + i * 4) = qv;
        lds[r][d]     = qv[0];
        lds[r][d + 1] = qv[1];
        lds[r][d + 2] = qv[2];
        lds[r][d + 3] = qv[3];
        s1 += v.x * w4Q[d] + v.y * w4Q[d + 1] + v.z * w4Q[d + 2] + v.w * w4Q[d + 3];
    }
    s1 += __shfl_xor(s1, 1);
    s1 += __shfl_xor(s1, 2);
    if ((t & 3) == 0) sub1[b * LQ + q0 + r] = s1;
    __syncthreads();
    int d = t >> 1, cb2 = (t & 1) * 32;
    bf16* dst = QbT + ((size_t)(b * DD + d)) * LQ + q0 + cb2;
#pragma unroll
    for (int m = 0; m < 4; ++m) {
        bf16x8 pk;
#pragma unroll
        for (int j = 0; j < 8; ++j) pk[j] = lds[cb2 + m * 8 + j][d];
        *(bf16x8*)(dst + m * 8) = pk;
    }
}

// ---------------------------------------------------------------------------
// K3: S = Cw @ Qb^T + sub0 + sub1 + bias; P = Qmask * exp(S - 8); Rinv = 1/rowsum(P)
// grid: (16, B) blocks, 256 threads (4 waves); block tile = 128 c x 256 q
// wave: 32 c-rows x 256 q; MFMA 16x16x32 bf16
// ---------------------------------------------------------------------------
__global__ __launch_bounds__(256) void k_s(const bf16* __restrict__ Cw,
    const bf16* __restrict__ Qb, const float* __restrict__ sub0,
    const float* __restrict__ sub1, const float* __restrict__ Qmask,
    const float* __restrict__ bias,
    bf16* __restrict__ P, float* __restrict__ Rinv)
{
    int b = blockIdx.y, ctile = blockIdx.x;
    int t = threadIdx.x, wid = t >> 6, lane = t & 63;
    int lr = lane & 15, lg = lane >> 4;
    int rowbase = ctile * 128 + wid * 32;

    f32x4 acc[2][16];
#pragma unroll
    for (int rt = 0; rt < 2; ++rt)
#pragma unroll
        for (int ct = 0; ct < 16; ++ct) acc[rt][ct] = (f32x4){0.f, 0.f, 0.f, 0.f};

    const bf16* Abase = Cw + ((size_t)(b * LC + rowbase + lr)) * DD + lg * 8;
    const bf16* Bbase = Qb + ((size_t)(b * LQ + lr)) * DD + lg * 8;
#pragma unroll
    for (int ks = 0; ks < 4; ++ks) {
        bf16x8 a0 = *(const bf16x8*)(Abase + ks * 32);
        bf16x8 a1 = *(const bf16x8*)(Abase + 16 * DD + ks * 32);
#pragma unroll
        for (int ct = 0; ct < 16; ++ct) {
            bf16x8 bb = *(const bf16x8*)(Bbase + (size_t)ct * 16 * DD + ks * 32);
            acc[0][ct] = MFMA16(a0, bb, acc[0][ct]);
            acc[1][ct] = MFMA16(a1, bb, acc[1][ct]);
        }
    }

    float biasv = bias[0];
    float sub0v[2][4];
#pragma unroll
    for (int rt = 0; rt < 2; ++rt)
#pragma unroll
        for (int j = 0; j < 4; ++j)
            sub0v[rt][j] = sub0[b * LC + rowbase + rt * 16 + lg * 4 + j];

    float rsum[2][4] = {};
#pragma unroll
    for (int ct = 0; ct < 16; ++ct) {
        int q = ct * 16 + lr;
        float s1v = sub1[b * LQ + q] + biasv;
        float qm = Qmask[b * LQ + q];
#pragma unroll
        for (int rt = 0; rt < 2; ++rt)
#pragma unroll
            for (int j = 0; j < 4; ++j) {
                float S = acc[rt][ct][j] + sub0v[rt][j] + s1v;
                float Pv = __expf(S - 8.0f) * qm;
                rsum[rt][j] += Pv;
                P[((size_t)(b * LC + rowbase + rt * 16 + lg * 4 + j)) * LQ + q] = (bf16)Pv;
            }
    }
#pragma unroll
    for (int rt = 0; rt < 2; ++rt)
#pragma unroll
        for (int j = 0; j < 4; ++j) {
            float s = rsum[rt][j];
            s += __shfl_xor(s, 1);
            s += __shfl_xor(s, 2);
            s += __shfl_xor(s, 4);
            s += __shfl_xor(s, 8);
            if (lr == 0) Rinv[b * LC + rowbase + rt * 16 + lg * 4 + j] = 1.0f / s;
        }
}

// ---------------------------------------------------------------------------
// K4: PT[q][c] = Cmask[c] * P[c][q] (bf16, exact since mask is 0/1),
//     Lpart[b][ctile][q] = sum over 64 c of that tile.
// grid: (4, 32, B), 256 threads; tile 64c x 64q via LDS transpose
// ---------------------------------------------------------------------------
__global__ __launch_bounds__(256) void k_t(const bf16* __restrict__ P,
    const float* __restrict__ Cmask, bf16* __restrict__ PT, float* __restrict__ Lpart)
{
    __shared__ bf16 lds[64][66];
    int qt = blockIdx.x, ct = blockIdx.y, b = blockIdx.z;
    int c0 = ct * 64, q0 = qt * 64;
    int t = threadIdx.x;
    int r = t >> 2, qb = (t & 3) * 16;
    float cm = Cmask[b * LC + c0 + r];
    const bf16* src = P + ((size_t)(b * LC + c0 + r)) * LQ + q0 + qb;
    bf16x8 v0 = ((const bf16x8*)src)[0];
    bf16x8 v1 = ((const bf16x8*)src)[1];
    bool keep = (cm != 0.0f);
#pragma unroll
    for (int j = 0; j < 8; ++j) {
        lds[r][qb + j]     = keep ? v0[j] : (bf16)0.f;
        lds[r][qb + 8 + j] = keep ? v1[j] : (bf16)0.f;
    }
    __syncthreads();
    int q = t >> 2, cb = (t & 3) * 16;
    float lsum = 0.f;
    bf16x8 o0, o1;
#pragma unroll
    for (int i = 0; i < 8; ++i) {
        bf16 x = lds[cb + i][q];
        o0[i] = x;
        lsum += (float)x;
    }
#pragma unroll
    for (int i = 0; i < 8; ++i) {
        bf16 x = lds[cb + 8 + i][q];
        o1[i] = x;
        lsum += (float)x;
    }
    bf16* dst = PT + ((size_t)(b * LQ + q0 + q)) * LC + c0 + cb;
    *(bf16x8*)dst = o0;
    *(bf16x8*)(dst + 8) = o1;
    lsum += __shfl_xor(lsum, 1);
    lsum += __shfl_xor(lsum, 2);
    if ((t & 3) == 0) Lpart[((size_t)(b * 32 + ct)) * LQ + q0 + q] = lsum;
}

// ---------------------------------------------------------------------------
// K5: Linv[b][q] = 1 / max(sum_ct Lpart, tiny)
// ---------------------------------------------------------------------------
__global__ __launch_bounds__(256) void k_lred(const float* __restrict__ Lpart,
                                              float* __restrict__ Linv)
{
    int b = blockIdx.x, q = threadIdx.x;
    float s = 0.f;
#pragma unroll
    for (int ct = 0; ct < 32; ++ct) s += Lpart[((size_t)(b * 32 + ct)) * LQ + q];
    Linv[b * LQ + q] = 1.0f / fmaxf(s, 1e-30f);
}

// ---------------------------------------------------------------------------
// K6: MT[d][q] = Linv[q] * sum_c CbT[d][c] * PT[q][c]   (= M^T with 1/L folded)
// grid: (4, B), 256 threads (4 waves); wave = 32 d x 64 q, K = 2048
// ---------------------------------------------------------------------------
__global__ __launch_bounds__(256) void k_m(const bf16* __restrict__ CbT,
    const bf16* __restrict__ PT, const float* __restrict__ Linv, bf16* __restrict__ MT)
{
    int qt = blockIdx.x, b = blockIdx.y;
    int q0 = qt * 64;
    int t = threadIdx.x, wid = t >> 6, lane = t & 63;
    int lr = lane & 15, lg = lane >> 4;
    int dbase = wid * 32;
    f32x4 acc[2][4];
#pragma unroll
    for (int rt = 0; rt < 2; ++rt)
#pragma unroll
        for (int ct = 0; ct < 4; ++ct) acc[rt][ct] = (f32x4){0.f, 0.f, 0.f, 0.f};

    const bf16* Abase = CbT + ((size_t)(b * DD + dbase + lr)) * LC + lg * 8;
    const bf16* Bbase = PT + ((size_t)(b * LQ + q0 + lr)) * LC + lg * 8;
#pragma unroll 4
    for (int ks = 0; ks < 64; ++ks) {
        bf16x8 a0 = *(const bf16x8*)(Abase + ks * 32);
        bf16x8 a1 = *(const bf16x8*)(Abase + (size_t)16 * LC + ks * 32);
#pragma unroll
        for (int ct = 0; ct < 4; ++ct) {
            bf16x8 bb = *(const bf16x8*)(Bbase + (size_t)ct * 16 * LC + ks * 32);
            acc[0][ct] = MFMA16(a0, bb, acc[0][ct]);
            acc[1][ct] = MFMA16(a1, bb, acc[1][ct]);
        }
    }
#pragma unroll
    for (int ct = 0; ct < 4; ++ct) {
        int q = q0 + ct * 16 + lr;
        float li = Linv[b * LQ + q];
#pragma unroll
        for (int rt = 0; rt < 2; ++rt)
#pragma unroll
            for (int j = 0; j < 4; ++j) {
                int d = dbase + rt * 16 + lg * 4 + j;
                MT[((size_t)(b * DD + d)) * LQ + q] = (bf16)(acc[rt][ct][j] * li);
            }
    }
}

// ---------------------------------------------------------------------------
// K7: A = Rinv * (P @ Qb), Bt = Rinv * (P @ M); write out[b][f][c]:
//     f<128: C ; 128..255: A ; 256..383: C*A ; 384..511: C*Bt  (all via LDS transpose)
// grid: (32, B), 256 threads (4 waves); block tile = 64 c, wave = 16 c x 128 d
// ---------------------------------------------------------------------------
__global__ __launch_bounds__(256) void k_out(const bf16* __restrict__ P,
    const bf16* __restrict__ QbT, const bf16* __restrict__ MT,
    const bf16* __restrict__ CbT, const float* __restrict__ Rinv,
    float* __restrict__ out)
{
    __shared__ float ldsA[DD][65];
    __shared__ float ldsB[DD][65];
    int ctile = blockIdx.x, b = blockIdx.y;
    int c0 = ctile * 64;
    int t = threadIdx.x, wid = t >> 6, lane = t & 63;
    int lr = lane & 15, lg = lane >> 4;

    f32x4 accA[8], accB[8];
#pragma unroll
    for (int ct = 0; ct < 8; ++ct) {
        accA[ct] = (f32x4){0.f, 0.f, 0.f, 0.f};
        accB[ct] = (f32x4){0.f, 0.f, 0.f, 0.f};
    }
    const bf16* Abase = P + ((size_t)(b * LC + c0 + wid * 16 + lr)) * LQ + lg * 8;
    const bf16* Qbase = QbT + ((size_t)(b * DD + lr)) * LQ + lg * 8;
    const bf16* Mbase = MT + ((size_t)(b * DD + lr)) * LQ + lg * 8;
#pragma unroll
    for (int ks = 0; ks < 8; ++ks) {
        bf16x8 a = *(const bf16x8*)(Abase + ks * 32);
#pragma unroll
        for (int ct = 0; ct < 8; ++ct) {
            bf16x8 bq = *(const bf16x8*)(Qbase + (size_t)ct * 16 * LQ + ks * 32);
            bf16x8 bm = *(const bf16x8*)(Mbase + (size_t)ct * 16 * LQ + ks * 32);
            accA[ct] = MFMA16(a, bq, accA[ct]);
            accB[ct] = MFMA16(a, bm, accB[ct]);
        }
    }
    float rinv[4];
#pragma unroll
    for (int j = 0; j < 4; ++j)
        rinv[j] = Rinv[b * LC + c0 + wid * 16 + lg * 4 + j];
#pragma unroll
    for (int ct = 0; ct < 8; ++ct)
#pragma unroll
        for (int j = 0; j < 4; ++j) {
            int d = ct * 16 + lr;
            int cl = wid * 16 + lg * 4 + j;
            ldsA[d][cl] = accA[ct][j] * rinv[j];
            ldsB[d][cl] = accB[ct][j] * rinv[j];
        }
    __syncthreads();

    const bf16* Crow = CbT + (size_t)(b * DD) * LC + c0;
    float* obase = out + (size_t)(b * 512) * LC + c0;
    int fsub = t >> 4;
    int cq = (t & 15) * 4;
#pragma unroll
    for (int iter = 0; iter < 8; ++iter) {
        int d = iter * 16 + fsub;
        const bf16* cp = Crow + (size_t)d * LC + cq;
        float c4[4], a4[4], b4[4];
#pragma unroll
        for (int i = 0; i < 4; ++i) {
            c4[i] = (float)cp[i];
            a4[i] = ldsA[d][cq + i];
            b4[i] = ldsB[d][cq + i];
        }
        *(float4*)(obase + (size_t)d * LC + cq) = (float4){c4[0], c4[1], c4[2], c4[3]};
        *(float4*)(obase + (size_t)(128 + d) * LC + cq) = (float4){a4[0], a4[1], a4[2], a4[3]};
        *(float4*)(obase + (size_t)(256 + d) * LC + cq) =
            (float4){c4[0] * a4[0], c4[1] * a4[1], c4[2] * a4[2], c4[3] * a4[3]};
        *(float4*)(obase + (size_t)(384 + d) * LC + cq) =
            (float4){c4[0] * b4[0], c4[1] * b4[1], c4[2] * b4[2], c4[3] * b4[3]};
    }
}

// ---------------------------------------------------------------------------
extern "C" void kernel_launch(void* const* d_in, const int* in_sizes, int n_in,
                              void* d_out, int out_size, void* d_ws, size_t ws_size,
                              hipStream_t stream)
{
    const float* C     = (const float*)d_in[0];
    const float* Q     = (const float*)d_in[1];
    const float* Cmask = (const float*)d_in[2];
    const float* Qmask = (const float*)d_in[3];
    const float* w4C   = (const float*)d_in[4];
    const float* w4Q   = (const float*)d_in[5];
    const float* w4mlu = (const float*)d_in[6];
    const float* bias  = (const float*)d_in[7];
    float* out = (float*)d_out;

    char* ws = (char*)d_ws;
    size_t off = 0;
    auto alloc = [&](size_t bytes) -> char* {
        char* p = ws + off;
        off += (bytes + 255) & ~(size_t)255;
        return p;
    };
    bf16* Cw    = (bf16*)alloc((size_t)B_ * LC * DD * 2);
    bf16* CbT   = (bf16*)alloc((size_t)B_ * LC * DD * 2);
    bf16* Qb    = (bf16*)alloc((size_t)B_ * LQ * DD * 2);
    bf16* QbT   = (bf16*)alloc((size_t)B_ * LQ * DD * 2);
    bf16* Pbuf  = (bf16*)alloc((size_t)B_ * LC * LQ * 2);
    bf16* PT    = (bf16*)alloc((size_t)B_ * LC * LQ * 2);
    bf16* MT    = (bf16*)alloc((size_t)B_ * DD * LQ * 2);
    float* sub0 = (float*)alloc((size_t)B_ * LC * 4);
    float* sub1 = (float*)alloc((size_t)B_ * LQ * 4);
    float* Rinv = (float*)alloc((size_t)B_ * LC * 4);
    float* Lpart = (float*)alloc((size_t)B_ * 32 * LQ * 4);
    float* Linv = (float*)alloc((size_t)B_ * LQ * 4);
    (void)ws_size; (void)in_sizes; (void)n_in; (void)out_size;

    hipLaunchKernelGGL(k_prep_c, dim3(B_ * 32), dim3(256), 0, stream, C, w4C, w4mlu, Cw, CbT, sub0);
    hipLaunchKernelGGL(k_prep_q, dim3(B_ * 4), dim3(256), 0, stream, Q, w4Q, Qb, QbT, sub1);
    hipLaunchKernelGGL(k_s, dim3(16, B_), dim3(256), 0, stream, Cw, Qb, sub0, sub1, Qmask, bias, Pbuf, Rinv);
    hipLaunchKernelGGL(k_t, dim3(4, 32, B_), dim3(256), 0, stream, Pbuf, Cmask, PT, Lpart);
    hipLaunchKernelGGL(k_lred, dim3(B_), dim3(256), 0, stream, Lpart, Linv);
    hipLaunchKernelGGL(k_m, dim3(4, B_), dim3(256), 0, stream, CbT, PT, Linv, MT);
    hipLaunchKernelGGL(k_out, dim3(32, B_), dim3(256), 0, stream, Pbuf, QbT, MT, CbT, Rinv, out);
}